// Round 2
// baseline (4545.037 us; speedup 1.0000x reference)
//
#include <hip/hip_runtime.h>
#include <stdint.h>

#define DEV __device__ __forceinline__

// ================= conv0: normalize + 3x3 s1 p1 + relu =================
// Weights read via wave-uniform (scalar) global loads — no LDS traffic.
__global__ __launch_bounds__(256) void k_conv0(
    const float* __restrict__ x, const float* __restrict__ W,
    const float* __restrict__ b, float* __restrict__ y0, int base)
{
  __shared__ float sIn[3][34][34];
  const int t = threadIdx.x;
  const long img = base + blockIdx.x;
  const float mean[3] = {0.4914f, 0.4822f, 0.4465f};
  const float stdv[3] = {0.2023f, 0.1994f, 0.201f};
  for (int i = t; i < 3 * 34 * 34; i += 256) {
    int c = i / 1156, r = i % 1156, yy = r / 34 - 1, xx = r % 34 - 1;
    float v = 0.f;
    if ((unsigned)yy < 32u && (unsigned)xx < 32u)
      v = (x[((img * 3 + c) * 32 + yy) * 32 + xx] - mean[c]) / stdv[c];
    (&sIn[0][0][0])[i] = v;
  }
  __syncthreads();
  for (int p = t; p < 1024; p += 256) {
    const int py = p >> 5, px = p & 31;
    float in[27];
#pragma unroll
    for (int c = 0; c < 3; c++)
#pragma unroll
      for (int ky = 0; ky < 3; ky++)
#pragma unroll
        for (int kx = 0; kx < 3; kx++)
          in[c * 9 + ky * 3 + kx] = sIn[c][py + ky][px + kx];
#pragma unroll 4
    for (int oc = 0; oc < 32; oc++) {
      float acc = b[oc];
      const float* wp = W + oc * 27;
#pragma unroll
      for (int k = 0; k < 27; k++) acc += in[k] * wp[k];
      y0[(((long)blockIdx.x * 32 + oc) * 32 + py) * 32 + px] = fmaxf(acc, 0.f);
    }
  }
}

// ================= conv2: 32->32, 4x4 s2 p1 + relu =================
// Parity-plane LDS (kills stride-2 bank conflicts) + scalar weights.
__global__ __launch_bounds__(256, 4) void k_conv2(
    const float* __restrict__ y0, const float* __restrict__ W,
    const float* __restrict__ b, float* __restrict__ y2)
{
  __shared__ float sP[2][2][8][17][17];   // 37 KB
  const int t = threadIdx.x;
  const int px = t & 15, py = t >> 4;
  float acc[32];
#pragma unroll
  for (int o = 0; o < 32; o++) acc[o] = b[o];
  for (int icp = 0; icp < 4; icp++) {
    __syncthreads();
    for (int i = t; i < 8 * 34 * 34; i += 256) {
      int c = i / 1156, r = i % 1156, iy = r / 34 - 1, ix = r % 34 - 1;
      float v = 0.f;
      if ((unsigned)iy < 32u && (unsigned)ix < 32u)
        v = y0[(((long)blockIdx.x * 32 + icp * 8 + c) * 32 + iy) * 32 + ix];
      sP[iy & 1][ix & 1][c][(iy + 1) >> 1][(ix + 1) >> 1] = v;
    }
    __syncthreads();
#pragma unroll 1
    for (int c = 0; c < 8; c++) {
      float in[16];
#pragma unroll
      for (int ky = 0; ky < 4; ky++)
#pragma unroll
        for (int kx = 0; kx < 4; kx++)
          in[ky * 4 + kx] = sP[(ky + 1) & 1][(kx + 1) & 1][c][(2 * py + ky) >> 1][(2 * px + kx) >> 1];
      const float* wp = W + (icp * 8 + c) * 16;   // W[(o*32 + ic)*16 + k]
#pragma unroll
      for (int o = 0; o < 32; o++)
#pragma unroll
        for (int k = 0; k < 16; k++)
          acc[o] += in[k] * wp[o * 512 + k];
    }
  }
#pragma unroll
  for (int o = 0; o < 32; o++)
    y2[(((long)blockIdx.x * 32 + o) * 16 + py) * 16 + px] = fmaxf(acc[o], 0.f);
}

// ================= conv4: 32->64, 3x3 s1 p1 + relu =================
// All 64 oc per thread, scalar weights, single input staging.
__global__ __launch_bounds__(256, 2) void k_conv4(
    const float* __restrict__ y2, const float* __restrict__ W,
    const float* __restrict__ b, float* __restrict__ y4)
{
  __shared__ float sIn[32][18][18];    // 41.5 KB
  const int t = threadIdx.x;
  const int px = t & 15, py = t >> 4;
  for (int i = t; i < 32 * 18 * 18; i += 256) {
    int c = i / 324, r = i % 324, yy = r / 18 - 1, xx = r % 18 - 1;
    float v = 0.f;
    if ((unsigned)yy < 16u && (unsigned)xx < 16u)
      v = y2[(((long)blockIdx.x * 32 + c) * 16 + yy) * 16 + xx];
    (&sIn[0][0][0])[i] = v;
  }
  __syncthreads();
  float acc[64];
#pragma unroll
  for (int o = 0; o < 64; o++) acc[o] = b[o];
#pragma unroll 1
  for (int c = 0; c < 32; c++) {
    float in[9];
#pragma unroll
    for (int ky = 0; ky < 3; ky++)
#pragma unroll
      for (int kx = 0; kx < 3; kx++)
        in[ky * 3 + kx] = sIn[c][py + ky][px + kx];
    const float* wp = W + c * 9;       // W[(o*32 + c)*9 + k]
#pragma unroll
    for (int o = 0; o < 64; o++)
#pragma unroll
      for (int k = 0; k < 9; k++)
        acc[o] += in[k] * wp[o * 288 + k];
  }
#pragma unroll
  for (int o = 0; o < 64; o++)
    y4[(((long)blockIdx.x * 64 + o) * 16 + py) * 16 + px] = fmaxf(acc[o], 0.f);
}

// ================= conv6: 4 experts as 64->256, 4x4 s2 p1 (no relu) =================
// Wave = 64 output channels (ocb = (t>>6)*64), lane = output pixel.
// Parity-plane input staging (stride-2 conflict-free), scalar weights.
__global__ __launch_bounds__(256, 2) void k_conv6(
    const float* __restrict__ y4, const float* __restrict__ W,
    const float* __restrict__ b, float* __restrict__ c6)
{
  __shared__ float sP[2][2][16][9][12];   // 27 KB
  const int t = threadIdx.x;
  const int p = t & 63, px = p & 7, py = p >> 3;
  const int ocb = __builtin_amdgcn_readfirstlane((t >> 6) * 64);
  float acc[64];
#pragma unroll
  for (int j = 0; j < 64; j++) acc[j] = b[ocb + j];
  for (int icp = 0; icp < 4; icp++) {
    __syncthreads();
    for (int i = t; i < 16 * 18 * 18; i += 256) {
      int c = i / 324, r = i % 324, iy = r / 18 - 1, ix = r % 18 - 1;
      float v = 0.f;
      if ((unsigned)iy < 16u && (unsigned)ix < 16u)
        v = y4[(((long)blockIdx.x * 64 + icp * 16 + c) * 16 + iy) * 16 + ix];
      sP[iy & 1][ix & 1][c][(iy + 1) >> 1][(ix + 1) >> 1] = v;
    }
    __syncthreads();
#pragma unroll 1
    for (int c = 0; c < 16; c++) {
      float in[16];
#pragma unroll
      for (int ky = 0; ky < 4; ky++)
#pragma unroll
        for (int kx = 0; kx < 4; kx++)
          in[ky * 4 + kx] = sP[(ky + 1) & 1][(kx + 1) & 1][c][(2 * py + ky) >> 1][(2 * px + kx) >> 1];
      const float* wp = W + ((long)ocb * 64 + icp * 16 + c) * 16;  // W[(oc*64+ic)*16+k]
#pragma unroll
      for (int j = 0; j < 64; j++)
#pragma unroll
        for (int k = 0; k < 16; k++)
          acc[j] += in[k] * wp[j * 1024 + k];
    }
  }
#pragma unroll
  for (int j = 0; j < 64; j++)
    c6[(((long)blockIdx.x * 256 + ocb + j) * 8 + py) * 8 + px] = acc[j];
}

// ================= generic fp32 tiled GEMM: 64(M) x 128(N), 4x8/thread ====
// C[M,N] = A[M,K] * B (+bias); B_NK: B is [N,K] row-major, else [K,N].
// SPLITK>1: writes partial (no bias/abs) at C + z*M*N.
// Two-level accumulation per 16-K tile for fp32 accuracy.
template<int B_NK, int DO_ABS, int SPLITK>
__global__ __launch_bounds__(256, 4) void k_gemm(
    const float* __restrict__ A, const float* __restrict__ Bm,
    const float* __restrict__ bias, float* __restrict__ C,
    int M, int N, int K)
{
  __shared__ float As[16][68];
  __shared__ float Bs[16][132];
  const int t = threadIdx.x;
  const int tx = t & 15, ty = t >> 4;
  const int n0 = blockIdx.x * 128, m0 = blockIdx.y * 64;
  const int Kc = K / SPLITK;
  const int k0 = blockIdx.z * Kc;
  float acc[4][8] = {{0.f}};
  for (int kt = 0; kt < Kc; kt += 16) {
    __syncthreads();
    {
      const int kc = t & 15, r0 = t >> 4;
#pragma unroll
      for (int i = 0; i < 4; i++)
        As[kc][r0 + 16 * i] = A[(long)(m0 + r0 + 16 * i) * K + k0 + kt + kc];
      if (B_NK) {
#pragma unroll
        for (int i = 0; i < 8; i++)
          Bs[kc][r0 + 16 * i] = Bm[(long)(n0 + r0 + 16 * i) * K + k0 + kt + kc];
      } else {
        const int nc = t & 127, kr0 = t >> 7;
#pragma unroll
        for (int i = 0; i < 8; i++)
          Bs[kr0 + 2 * i][nc] = Bm[(long)(k0 + kt + kr0 + 2 * i) * N + n0 + nc];
      }
    }
    __syncthreads();
    float part[4][8] = {{0.f}};
#pragma unroll
    for (int k = 0; k < 16; k++) {
      float4 av = *(const float4*)&As[k][ty * 4];
      float4 b0 = *(const float4*)&Bs[k][tx * 4];
      float4 b1 = *(const float4*)&Bs[k][64 + tx * 4];
      const float a[4] = {av.x, av.y, av.z, av.w};
      const float bb[8] = {b0.x, b0.y, b0.z, b0.w, b1.x, b1.y, b1.z, b1.w};
#pragma unroll
      for (int i = 0; i < 4; i++)
#pragma unroll
        for (int j = 0; j < 8; j++)
          part[i][j] += a[i] * bb[j];
    }
#pragma unroll
    for (int i = 0; i < 4; i++)
#pragma unroll
      for (int j = 0; j < 8; j++)
        acc[i][j] += part[i][j];
  }
#pragma unroll
  for (int i = 0; i < 4; i++) {
    const long m = m0 + ty * 4 + i;
    float v0[4], v1[4];
#pragma unroll
    for (int j = 0; j < 4; j++) {
      float u = acc[i][j], w = acc[i][j + 4];
      if (SPLITK == 1) {
        u += bias[n0 + tx * 4 + j];
        w += bias[n0 + 64 + tx * 4 + j];
        if (DO_ABS) { u = fabsf(u); w = fabsf(w); }
      }
      v0[j] = u; v1[j] = w;
    }
    float* dst = (SPLITK == 1) ? (C + m * N) : (C + ((long)blockIdx.z * M + m) * N);
    *(float4*)(dst + n0 + tx * 4) = make_float4(v0[0], v0[1], v0[2], v0[3]);
    *(float4*)(dst + n0 + 64 + tx * 4) = make_float4(v1[0], v1[1], v1[2], v1[3]);
  }
}

// ================= split-K reduce for scores6 (16 partials) =================
__global__ __launch_bounds__(256) void k_reduce6(
    const float* __restrict__ part, const float* __restrict__ br,
    float* __restrict__ s6, int rows)
{
  const int i = blockIdx.x * 256 + threadIdx.x;
  const int tot = rows * 256;
  if (i < tot) {
    float s = br[i & 255];
#pragma unroll
    for (int z = 0; z < 16; z++) s += part[z * tot + i];
    s6[i] = fabsf(s);
  }
}

// ================= block helpers =================
DEV int blk_reduce(int v, volatile int* sW4) {
#pragma unroll
  for (int d = 32; d > 0; d >>= 1) v += __shfl_down(v, d);
  const int lane = threadIdx.x & 63, wid = threadIdx.x >> 6;
  if (lane == 0) sW4[wid] = v;
  __syncthreads();
  int tot = sW4[0] + sW4[1] + sW4[2] + sW4[3];
  __syncthreads();
  return tot;
}

DEV int blk_exscan(int v, volatile int* sW4) {
  const int lane = threadIdx.x & 63, wid = threadIdx.x >> 6;
  int inc = v;
#pragma unroll
  for (int d = 1; d < 64; d <<= 1) {
    int u = __shfl_up(inc, d);
    if (lane >= d) inc += u;
  }
  if (lane == 63) sW4[wid] = inc;
  __syncthreads();
  int off = 0;
#pragma unroll
  for (int w = 0; w < 3; w++)
    if (w < wid) off += sW4[w];
  __syncthreads();
  return off + inc - v;
}

// ================= top-k select + gather (+relu) =================
template<int N, int KEEP, int SPATIAL>
__global__ __launch_bounds__(256) void k_topk(
    const float* __restrict__ scores, const float* __restrict__ full,
    float* __restrict__ out)
{
  constexpr int E = N / 256;
  __shared__ int sW4[4];
  __shared__ int sSel[KEEP];
  const int t = threadIdx.x;
  const long row = blockIdx.x;
  uint32_t kk[E];
#pragma unroll
  for (int e = 0; e < E; e++) kk[e] = __float_as_uint(scores[row * N + t * E + e]);
  uint32_t prefix = 0u;
  for (int bit = 31; bit >= 0; bit--) {
    uint32_t cand = prefix | (1u << bit);
    int c = 0;
#pragma unroll
    for (int e = 0; e < E; e++) c += (kk[e] >= cand) ? 1 : 0;
    if (blk_reduce(c, sW4) >= KEEP) prefix = cand;
  }
  int myG = 0, myE = 0;
#pragma unroll
  for (int e = 0; e < E; e++) { myG += kk[e] > prefix; myE += kk[e] == prefix; }
  const int G = blk_reduce(myG, sW4);
  const int needEq = KEEP - G;
  const int prefE = blk_exscan(myE, sW4);
  const int keepcnt = myG + max(0, min(myE, needEq - prefE));
  int pos = blk_exscan(keepcnt, sW4);
  int eqSeen = prefE;
#pragma unroll
  for (int e = 0; e < E; e++) {
    const bool kp = (kk[e] > prefix) || ((kk[e] == prefix) && (eqSeen < needEq));
    if (kk[e] == prefix) eqSeen++;
    if (kp) sSel[pos++] = t * E + e;
  }
  __syncthreads();
  if (SPATIAL) {
    for (int i = t; i < KEEP * 64; i += 256)
      out[row * (KEEP * 64) + i] = fmaxf(full[(row * N + sSel[i >> 6]) * 64 + (i & 63)], 0.f);
  } else {
    for (int i = t; i < KEEP; i += 256)
      out[row * KEEP + i] = fmaxf(full[row * N + sSel[i]], 0.f);
  }
}

// ================= final: lin13 + scores13 + top-10-of-40 =================
__global__ __launch_bounds__(256) void k_final(
    const float* __restrict__ y11, const float* __restrict__ W13,
    const float* __restrict__ b13, const float* __restrict__ Wr13,
    const float* __restrict__ br13, float* __restrict__ outp)
{
  __shared__ float sX[512];
  __shared__ float sL[64];
  __shared__ float sS[64];
  const int t = threadIdx.x;
  const long row = blockIdx.x;
  for (int i = t; i < 512; i += 256) sX[i] = y11[row * 512 + i];
  __syncthreads();
  if (t < 40) {
    float acc = b13[t];
    const float4* w4 = (const float4*)(W13 + t * 512);
    for (int k = 0; k < 128; k++) {
      float4 w = w4[k];
      acc += sX[4 * k] * w.x + sX[4 * k + 1] * w.y + sX[4 * k + 2] * w.z + sX[4 * k + 3] * w.w;
    }
    sL[t] = acc;
  } else if (t >= 64 && t < 104) {
    const int n = t - 64;
    float acc = br13[n];
    for (int k = 0; k < 512; k++) acc += sX[k] * Wr13[k * 40 + n];
    sS[n] = fabsf(acc);
  }
  __syncthreads();
  if (t < 64) {
    const uint32_t key = (t < 40) ? __float_as_uint(sS[t]) : 0u;
    uint32_t prefix = 0u;
#pragma unroll
    for (int bit = 31; bit >= 0; bit--) {
      uint32_t cand = prefix | (1u << bit);
      unsigned long long m = __ballot(t < 40 && key >= cand);
      if (__popcll(m) >= 10) prefix = cand;
    }
    const int G = __popcll(__ballot(t < 40 && key > prefix));
    const int needEq = 10 - G;
    const unsigned long long me = __ballot(t < 40 && key == prefix);
    const unsigned long long lt = (t == 0) ? 0ull : (~0ull >> (64 - t));
    const int eqr = __popcll(me & lt);
    const bool kp = (t < 40) && ((key > prefix) || (key == prefix && eqr < needEq));
    const int pos = __popcll(__ballot(kp) & lt);
    if (kp) outp[row * 10 + pos] = sL[t];
  }
}

// ================= launch =================
extern "C" void kernel_launch(void* const* d_in, const int* in_sizes, int n_in,
                              void* d_out, int out_size, void* d_ws, size_t ws_size,
                              hipStream_t stream)
{
  const float* x    = (const float*)d_in[0];
  const float* W0   = (const float*)d_in[1];
  const float* b0   = (const float*)d_in[2];
  const float* W2   = (const float*)d_in[3];
  const float* b2   = (const float*)d_in[4];
  const float* W4   = (const float*)d_in[5];
  const float* b4   = (const float*)d_in[6];
  const float* W6   = (const float*)d_in[7];   // [256,64,4,4]
  const float* b6   = (const float*)d_in[8];   // [256]
  const float* Wr6  = (const float*)d_in[9];   // [16384,256]
  const float* br6  = (const float*)d_in[10];
  const float* W9   = (const float*)d_in[11];  // [2048,4096]  (N,K)
  const float* b9   = (const float*)d_in[12];
  const float* Wr9  = (const float*)d_in[13];  // [4096,2048]  (K,N)
  const float* br9  = (const float*)d_in[14];
  const float* W11  = (const float*)d_in[15];  // [2048,512]
  const float* b11  = (const float*)d_in[16];
  const float* Wr11 = (const float*)d_in[17];  // [512,2048]
  const float* br11 = (const float*)d_in[18];
  const float* W13  = (const float*)d_in[19];  // [40,512]
  const float* b13  = (const float*)d_in[20];
  const float* Wr13 = (const float*)d_in[21];  // [512,40]
  const float* br13 = (const float*)d_in[22];
  float* out = (float*)d_out;
  float* ws = (float*)d_ws;

  // Workspace layout (floats); total = 25,165,824 floats = 96 MB.
  float* R0  = ws;                           // 16,777,216 floats
  float* R1  = ws + 16777216;                //  4,194,304 floats
  float* y6  = ws + 16777216 + 4194304;      //  4,194,304 floats [1024,4096]
  // chunk-local aliases (conv pipeline, 512 images per chunk):
  float* y0c = R0;                           // [512,32,32,32]
  float* y4c = R0;                           // [512,64,16,16] (y0 dead)
  float* c6c = R0 + 8388608;                 // [512,256,8,8]
  float* y2c = R1;                           // [512,32,16,16]
  float* s6  = R1;                           // [512,256] (y2 dead)
  float* p6  = R1 + 262144;                  // splitK partials 16*512*256
  // linear-stage slots inside R0 (conv buffers dead):
  float* l9  = R0;                           // [1024,2048]
  float* s9  = R0 + 2097152;                 // [1024,2048]
  float* y9  = R0 + 4194304;                 // [1024,512]
  float* l11 = R0 + 4718592;                 // [1024,2048]
  float* s11 = R0 + 6815744;                 // [1024,2048]
  float* y11 = R0 + 8912896;                 // [1024,512]

  for (int chunk = 0; chunk < 2; chunk++) {
    const int base = chunk * 512;
    k_conv0<<<512, 256, 0, stream>>>(x, W0, b0, y0c, base);
    k_conv2<<<512, 256, 0, stream>>>(y0c, W2, b2, y2c);
    k_conv4<<<512, 256, 0, stream>>>(y2c, W4, b4, y4c);
    k_conv6<<<512, 256, 0, stream>>>(y4c, W6, b6, c6c);
    dim3 g6(256 / 128, 512 / 64, 16);
    k_gemm<0, 0, 16><<<g6, 256, 0, stream>>>(y4c, Wr6, nullptr, p6, 512, 256, 16384);
    k_reduce6<<<512, 256, 0, stream>>>(p6, br6, s6, 512);
    k_topk<256, 64, 1><<<512, 256, 0, stream>>>(s6, c6c, y6 + (long)base * 4096);
  }

  dim3 g9(2048 / 128, 1024 / 64, 1);
  k_gemm<1, 0, 1><<<g9, 256, 0, stream>>>(y6, W9, b9, l9, 1024, 2048, 4096);
  k_gemm<0, 1, 1><<<g9, 256, 0, stream>>>(y6, Wr9, br9, s9, 1024, 2048, 4096);
  k_topk<2048, 512, 0><<<1024, 256, 0, stream>>>(s9, l9, y9);

  k_gemm<1, 0, 1><<<g9, 256, 0, stream>>>(y9, W11, b11, l11, 1024, 2048, 512);
  k_gemm<0, 1, 1><<<g9, 256, 0, stream>>>(y9, Wr11, br11, s11, 1024, 2048, 512);
  k_topk<2048, 512, 0><<<1024, 256, 0, stream>>>(s11, l11, y11);

  k_final<<<1024, 256, 0, stream>>>(y11, W13, b13, Wr13, br13, out);
}

// Round 3
// 3283.315 us; speedup vs baseline: 1.3843x; 1.3843x over previous
//
#include <hip/hip_runtime.h>
#include <stdint.h>

#define DEV __device__ __forceinline__

// ================= conv0: normalize + 3x3 s1 p1 + relu =================
__global__ __launch_bounds__(256) void k_conv0(
    const float* __restrict__ x, const float* __restrict__ W,
    const float* __restrict__ b, float* __restrict__ y0, int base)
{
  __shared__ float sIn[3][34][34];
  const int t = threadIdx.x;
  const long img = base + blockIdx.x;
  const float mean[3] = {0.4914f, 0.4822f, 0.4465f};
  const float stdv[3] = {0.2023f, 0.1994f, 0.201f};
  for (int i = t; i < 3 * 34 * 34; i += 256) {
    int c = i / 1156, r = i % 1156, yy = r / 34 - 1, xx = r % 34 - 1;
    float v = 0.f;
    if ((unsigned)yy < 32u && (unsigned)xx < 32u)
      v = (x[((img * 3 + c) * 32 + yy) * 32 + xx] - mean[c]) / stdv[c];
    (&sIn[0][0][0])[i] = v;
  }
  __syncthreads();
  for (int p = t; p < 1024; p += 256) {
    const int py = p >> 5, px = p & 31;
    float in[27];
#pragma unroll
    for (int c = 0; c < 3; c++)
#pragma unroll
      for (int ky = 0; ky < 3; ky++)
#pragma unroll
        for (int kx = 0; kx < 3; kx++)
          in[c * 9 + ky * 3 + kx] = sIn[c][py + ky][px + kx];
#pragma unroll 4
    for (int oc = 0; oc < 32; oc++) {
      float acc = b[oc];
      const float* wp = W + oc * 27;
#pragma unroll
      for (int k = 0; k < 27; k++) acc += in[k] * wp[k];
      y0[(((long)blockIdx.x * 32 + oc) * 32 + py) * 32 + px] = fmaxf(acc, 0.f);
    }
  }
}

// ================= conv2: 32->32, 4x4 s2 p1 + relu =================
// Parity-plane LDS (kills stride-2 bank conflicts) + scalar weights.
__global__ __launch_bounds__(256, 4) void k_conv2(
    const float* __restrict__ y0, const float* __restrict__ W,
    const float* __restrict__ b, float* __restrict__ y2)
{
  __shared__ float sP[2][2][8][17][17];   // 37 KB
  const int t = threadIdx.x;
  const int px = t & 15, py = t >> 4;
  float acc[32];
#pragma unroll
  for (int o = 0; o < 32; o++) acc[o] = b[o];
  for (int icp = 0; icp < 4; icp++) {
    __syncthreads();
    for (int i = t; i < 8 * 34 * 34; i += 256) {
      int c = i / 1156, r = i % 1156, iy = r / 34 - 1, ix = r % 34 - 1;
      float v = 0.f;
      if ((unsigned)iy < 32u && (unsigned)ix < 32u)
        v = y0[(((long)blockIdx.x * 32 + icp * 8 + c) * 32 + iy) * 32 + ix];
      sP[iy & 1][ix & 1][c][(iy + 1) >> 1][(ix + 1) >> 1] = v;
    }
    __syncthreads();
#pragma unroll 1
    for (int c = 0; c < 8; c++) {
      float in[16];
#pragma unroll
      for (int ky = 0; ky < 4; ky++)
#pragma unroll
        for (int kx = 0; kx < 4; kx++)
          in[ky * 4 + kx] = sP[(ky + 1) & 1][(kx + 1) & 1][c][(2 * py + ky) >> 1][(2 * px + kx) >> 1];
      const float* wp = W + (icp * 8 + c) * 16;   // W[(o*32 + ic)*16 + k]
#pragma unroll
      for (int o = 0; o < 32; o++) {
        float s = 0.f;
#pragma unroll
        for (int k = 0; k < 16; k++)
          s += in[k] * wp[o * 512 + k];
        acc[o] += s;
      }
    }
  }
#pragma unroll
  for (int o = 0; o < 32; o++)
    y2[(((long)blockIdx.x * 32 + o) * 16 + py) * 16 + px] = fmaxf(acc[o], 0.f);
}

// ================= conv4: 32->64, 3x3 s1 p1 + relu =================
__global__ __launch_bounds__(256, 2) void k_conv4(
    const float* __restrict__ y2, const float* __restrict__ W,
    const float* __restrict__ b, float* __restrict__ y4)
{
  __shared__ float sIn[32][18][18];    // 41.5 KB
  const int t = threadIdx.x;
  const int px = t & 15, py = t >> 4;
  for (int i = t; i < 32 * 18 * 18; i += 256) {
    int c = i / 324, r = i % 324, yy = r / 18 - 1, xx = r % 18 - 1;
    float v = 0.f;
    if ((unsigned)yy < 16u && (unsigned)xx < 16u)
      v = y2[(((long)blockIdx.x * 32 + c) * 16 + yy) * 16 + xx];
    (&sIn[0][0][0])[i] = v;
  }
  __syncthreads();
  float acc[64];
#pragma unroll
  for (int o = 0; o < 64; o++) acc[o] = b[o];
#pragma unroll 1
  for (int c = 0; c < 32; c++) {
    float in[9];
#pragma unroll
    for (int ky = 0; ky < 3; ky++)
#pragma unroll
      for (int kx = 0; kx < 3; kx++)
        in[ky * 3 + kx] = sIn[c][py + ky][px + kx];
    const float* wp = W + c * 9;       // W[(o*32 + c)*9 + k]
#pragma unroll
    for (int o = 0; o < 64; o++) {
      float s = 0.f;
#pragma unroll
      for (int k = 0; k < 9; k++)
        s += in[k] * wp[o * 288 + k];
      acc[o] += s;
    }
  }
#pragma unroll
  for (int o = 0; o < 64; o++)
    y4[(((long)blockIdx.x * 64 + o) * 16 + py) * 16 + px] = fmaxf(acc[o], 0.f);
}

// ================= conv6: 4 experts as 64->256, 4x4 s2 p1 (no relu) ======
// grid = (512 img, 4 ocg). Block owns 64 oc; thread = (pixel lane, ocq=t>>6)
// -> acc[16] (no spill). Input staged once per icp; weights via wave-uniform
// scalar loads (conv2-proven pattern).
__global__ __launch_bounds__(256, 2) void k_conv6(
    const float* __restrict__ y4, const float* __restrict__ W,
    const float* __restrict__ b, float* __restrict__ c6)
{
  __shared__ float sIn[16][18][18];   // 20.7 KB
  const int t = threadIdx.x;
  const int p = t & 63, px = p & 7, py = p >> 3;
  const int ocb = __builtin_amdgcn_readfirstlane(blockIdx.y * 64 + (t >> 6) * 16);
  float acc[16];
#pragma unroll
  for (int o = 0; o < 16; o++) acc[o] = b[ocb + o];
  for (int icp = 0; icp < 4; icp++) {
    __syncthreads();
    for (int i = t; i < 16 * 18 * 18; i += 256) {
      int c = i / 324, r = i % 324, iy = r / 18 - 1, ix = r % 18 - 1;
      float v = 0.f;
      if ((unsigned)iy < 16u && (unsigned)ix < 16u)
        v = y4[(((long)blockIdx.x * 64 + icp * 16 + c) * 16 + iy) * 16 + ix];
      (&sIn[0][0][0])[i] = v;
    }
    __syncthreads();
#pragma unroll 1
    for (int c = 0; c < 16; c++) {
      float in[16];
#pragma unroll
      for (int ky = 0; ky < 4; ky++)
#pragma unroll
        for (int kx = 0; kx < 4; kx++)
          in[ky * 4 + kx] = sIn[c][2 * py + ky][2 * px + kx];
      const float* wp = W + ((long)ocb * 64 + icp * 16 + c) * 16;  // W[(oc*64+ic)*16+k]
#pragma unroll
      for (int o = 0; o < 16; o++) {
        float s = 0.f;
#pragma unroll
        for (int k = 0; k < 16; k++)
          s += in[k] * wp[o * 1024 + k];
        acc[o] += s;
      }
    }
  }
#pragma unroll
  for (int o = 0; o < 16; o++)
    c6[(((long)blockIdx.x * 256 + ocb + o) * 8 + py) * 8 + px] = acc[o];
}

// ================= generic fp32 tiled GEMM: 64(M) x 128(N), 4x8/thread ====
template<int B_NK, int DO_ABS, int SPLITK>
__global__ __launch_bounds__(256, 4) void k_gemm(
    const float* __restrict__ A, const float* __restrict__ Bm,
    const float* __restrict__ bias, float* __restrict__ C,
    int M, int N, int K)
{
  __shared__ float As[16][68];
  __shared__ float Bs[16][132];
  const int t = threadIdx.x;
  const int tx = t & 15, ty = t >> 4;
  const int n0 = blockIdx.x * 128, m0 = blockIdx.y * 64;
  const int Kc = K / SPLITK;
  const int k0 = blockIdx.z * Kc;
  float acc[4][8] = {{0.f}};
  for (int kt = 0; kt < Kc; kt += 16) {
    __syncthreads();
    {
      const int kc = t & 15, r0 = t >> 4;
#pragma unroll
      for (int i = 0; i < 4; i++)
        As[kc][r0 + 16 * i] = A[(long)(m0 + r0 + 16 * i) * K + k0 + kt + kc];
      if (B_NK) {
#pragma unroll
        for (int i = 0; i < 8; i++)
          Bs[kc][r0 + 16 * i] = Bm[(long)(n0 + r0 + 16 * i) * K + k0 + kt + kc];
      } else {
        const int nc = t & 127, kr0 = t >> 7;
#pragma unroll
        for (int i = 0; i < 8; i++)
          Bs[kr0 + 2 * i][nc] = Bm[(long)(k0 + kt + kr0 + 2 * i) * N + n0 + nc];
      }
    }
    __syncthreads();
    float part[4][8] = {{0.f}};
#pragma unroll
    for (int k = 0; k < 16; k++) {
      float4 av = *(const float4*)&As[k][ty * 4];
      float4 b0 = *(const float4*)&Bs[k][tx * 4];
      float4 b1 = *(const float4*)&Bs[k][64 + tx * 4];
      const float a[4] = {av.x, av.y, av.z, av.w};
      const float bb[8] = {b0.x, b0.y, b0.z, b0.w, b1.x, b1.y, b1.z, b1.w};
#pragma unroll
      for (int i = 0; i < 4; i++)
#pragma unroll
        for (int j = 0; j < 8; j++)
          part[i][j] += a[i] * bb[j];
    }
#pragma unroll
    for (int i = 0; i < 4; i++)
#pragma unroll
      for (int j = 0; j < 8; j++)
        acc[i][j] += part[i][j];
  }
#pragma unroll
  for (int i = 0; i < 4; i++) {
    const long m = m0 + ty * 4 + i;
    float v0[4], v1[4];
#pragma unroll
    for (int j = 0; j < 4; j++) {
      float u = acc[i][j], w = acc[i][j + 4];
      if (SPLITK == 1) {
        u += bias[n0 + tx * 4 + j];
        w += bias[n0 + 64 + tx * 4 + j];
        if (DO_ABS) { u = fabsf(u); w = fabsf(w); }
      }
      v0[j] = u; v1[j] = w;
    }
    float* dst = (SPLITK == 1) ? (C + m * N) : (C + ((long)blockIdx.z * M + m) * N);
    *(float4*)(dst + n0 + tx * 4) = make_float4(v0[0], v0[1], v0[2], v0[3]);
    *(float4*)(dst + n0 + 64 + tx * 4) = make_float4(v1[0], v1[1], v1[2], v1[3]);
  }
}

// ================= split-K reduce for scores6 (16 partials) =================
__global__ __launch_bounds__(256) void k_reduce6(
    const float* __restrict__ part, const float* __restrict__ br,
    float* __restrict__ s6, int rows)
{
  const int i = blockIdx.x * 256 + threadIdx.x;
  const int tot = rows * 256;
  if (i < tot) {
    float s = br[i & 255];
#pragma unroll
    for (int z = 0; z < 16; z++) s += part[z * tot + i];
    s6[i] = fabsf(s);
  }
}

// ================= block helpers =================
DEV int blk_reduce(int v, volatile int* sW4) {
#pragma unroll
  for (int d = 32; d > 0; d >>= 1) v += __shfl_down(v, d);
  const int lane = threadIdx.x & 63, wid = threadIdx.x >> 6;
  if (lane == 0) sW4[wid] = v;
  __syncthreads();
  int tot = sW4[0] + sW4[1] + sW4[2] + sW4[3];
  __syncthreads();
  return tot;
}

DEV int blk_exscan(int v, volatile int* sW4) {
  const int lane = threadIdx.x & 63, wid = threadIdx.x >> 6;
  int inc = v;
#pragma unroll
  for (int d = 1; d < 64; d <<= 1) {
    int u = __shfl_up(inc, d);
    if (lane >= d) inc += u;
  }
  if (lane == 63) sW4[wid] = inc;
  __syncthreads();
  int off = 0;
#pragma unroll
  for (int w = 0; w < 3; w++)
    if (w < wid) off += sW4[w];
  __syncthreads();
  return off + inc - v;
}

// ================= top-k select + gather (+relu) =================
template<int N, int KEEP, int SPATIAL>
__global__ __launch_bounds__(256) void k_topk(
    const float* __restrict__ scores, const float* __restrict__ full,
    float* __restrict__ out)
{
  constexpr int E = N / 256;
  __shared__ int sW4[4];
  __shared__ int sSel[KEEP];
  const int t = threadIdx.x;
  const long row = blockIdx.x;
  uint32_t kk[E];
#pragma unroll
  for (int e = 0; e < E; e++) kk[e] = __float_as_uint(scores[row * N + t * E + e]);
  uint32_t prefix = 0u;
  for (int bit = 31; bit >= 0; bit--) {
    uint32_t cand = prefix | (1u << bit);
    int c = 0;
#pragma unroll
    for (int e = 0; e < E; e++) c += (kk[e] >= cand) ? 1 : 0;
    if (blk_reduce(c, sW4) >= KEEP) prefix = cand;
  }
  int myG = 0, myE = 0;
#pragma unroll
  for (int e = 0; e < E; e++) { myG += kk[e] > prefix; myE += kk[e] == prefix; }
  const int G = blk_reduce(myG, sW4);
  const int needEq = KEEP - G;
  const int prefE = blk_exscan(myE, sW4);
  const int keepcnt = myG + max(0, min(myE, needEq - prefE));
  int pos = blk_exscan(keepcnt, sW4);
  int eqSeen = prefE;
#pragma unroll
  for (int e = 0; e < E; e++) {
    const bool kp = (kk[e] > prefix) || ((kk[e] == prefix) && (eqSeen < needEq));
    if (kk[e] == prefix) eqSeen++;
    if (kp) sSel[pos++] = t * E + e;
  }
  __syncthreads();
  if (SPATIAL) {
    for (int i = t; i < KEEP * 64; i += 256)
      out[row * (KEEP * 64) + i] = fmaxf(full[(row * N + sSel[i >> 6]) * 64 + (i & 63)], 0.f);
  } else {
    for (int i = t; i < KEEP; i += 256)
      out[row * KEEP + i] = fmaxf(full[row * N + sSel[i]], 0.f);
  }
}

// ================= final: lin13 + scores13 + top-10-of-40 =================
__global__ __launch_bounds__(256) void k_final(
    const float* __restrict__ y11, const float* __restrict__ W13,
    const float* __restrict__ b13, const float* __restrict__ Wr13,
    const float* __restrict__ br13, float* __restrict__ outp)
{
  __shared__ float sX[512];
  __shared__ float sL[64];
  __shared__ float sS[64];
  const int t = threadIdx.x;
  const long row = blockIdx.x;
  for (int i = t; i < 512; i += 256) sX[i] = y11[row * 512 + i];
  __syncthreads();
  if (t < 40) {
    float acc = b13[t];
    const float4* w4 = (const float4*)(W13 + t * 512);
    for (int k = 0; k < 128; k++) {
      float4 w = w4[k];
      acc += sX[4 * k] * w.x + sX[4 * k + 1] * w.y + sX[4 * k + 2] * w.z + sX[4 * k + 3] * w.w;
    }
    sL[t] = acc;
  } else if (t >= 64 && t < 104) {
    const int n = t - 64;
    float acc = br13[n];
    for (int k = 0; k < 512; k++) acc += sX[k] * Wr13[k * 40 + n];
    sS[n] = fabsf(acc);
  }
  __syncthreads();
  if (t < 64) {
    const uint32_t key = (t < 40) ? __float_as_uint(sS[t]) : 0u;
    uint32_t prefix = 0u;
#pragma unroll
    for (int bit = 31; bit >= 0; bit--) {
      uint32_t cand = prefix | (1u << bit);
      unsigned long long m = __ballot(t < 40 && key >= cand);
      if (__popcll(m) >= 10) prefix = cand;
    }
    const int G = __popcll(__ballot(t < 40 && key > prefix));
    const int needEq = 10 - G;
    const unsigned long long me = __ballot(t < 40 && key == prefix);
    const unsigned long long lt = (t == 0) ? 0ull : (~0ull >> (64 - t));
    const int eqr = __popcll(me & lt);
    const bool kp = (t < 40) && ((key > prefix) || (key == prefix && eqr < needEq));
    const int pos = __popcll(__ballot(kp) & lt);
    if (kp) outp[row * 10 + pos] = sL[t];
  }
}

// ================= launch =================
extern "C" void kernel_launch(void* const* d_in, const int* in_sizes, int n_in,
                              void* d_out, int out_size, void* d_ws, size_t ws_size,
                              hipStream_t stream)
{
  const float* x    = (const float*)d_in[0];
  const float* W0   = (const float*)d_in[1];
  const float* b0   = (const float*)d_in[2];
  const float* W2   = (const float*)d_in[3];
  const float* b2   = (const float*)d_in[4];
  const float* W4   = (const float*)d_in[5];
  const float* b4   = (const float*)d_in[6];
  const float* W6   = (const float*)d_in[7];   // [256,64,4,4]
  const float* b6   = (const float*)d_in[8];   // [256]
  const float* Wr6  = (const float*)d_in[9];   // [16384,256]
  const float* br6  = (const float*)d_in[10];
  const float* W9   = (const float*)d_in[11];  // [2048,4096]  (N,K)
  const float* b9   = (const float*)d_in[12];
  const float* Wr9  = (const float*)d_in[13];  // [4096,2048]  (K,N)
  const float* br9  = (const float*)d_in[14];
  const float* W11  = (const float*)d_in[15];  // [2048,512]
  const float* b11  = (const float*)d_in[16];
  const float* Wr11 = (const float*)d_in[17];  // [512,2048]
  const float* br11 = (const float*)d_in[18];
  const float* W13  = (const float*)d_in[19];  // [40,512]
  const float* b13  = (const float*)d_in[20];
  const float* Wr13 = (const float*)d_in[21];  // [512,40]
  const float* br13 = (const float*)d_in[22];
  float* out = (float*)d_out;
  float* ws = (float*)d_ws;

  // Workspace layout (floats); total = 25,165,824 floats = 96 MB.
  float* R0  = ws;                           // 16,777,216 floats
  float* R1  = ws + 16777216;                //  4,194,304 floats
  float* y6  = ws + 16777216 + 4194304;      //  4,194,304 floats [1024,4096]
  // chunk-local aliases (conv pipeline, 512 images per chunk):
  float* y0c = R0;                           // [512,32,32,32]
  float* y4c = R0;                           // [512,64,16,16] (y0 dead)
  float* c6c = R0 + 8388608;                 // [512,256,8,8]
  float* y2c = R1;                           // [512,32,16,16]
  float* s6  = R1;                           // [512,256] (y2 dead)
  float* p6  = R1 + 262144;                  // splitK partials 16*512*256
  // linear-stage slots inside R0 (conv buffers dead):
  float* l9  = R0;                           // [1024,2048]
  float* s9  = R0 + 2097152;                 // [1024,2048]
  float* y9  = R0 + 4194304;                 // [1024,512]
  float* l11 = R0 + 4718592;                 // [1024,2048]
  float* s11 = R0 + 6815744;                 // [1024,2048]
  float* y11 = R0 + 8912896;                 // [1024,512]

  for (int chunk = 0; chunk < 2; chunk++) {
    const int base = chunk * 512;
    k_conv0<<<512, 256, 0, stream>>>(x, W0, b0, y0c, base);
    k_conv2<<<512, 256, 0, stream>>>(y0c, W2, b2, y2c);
    k_conv4<<<512, 256, 0, stream>>>(y2c, W4, b4, y4c);
    dim3 gc6(512, 4);
    k_conv6<<<gc6, 256, 0, stream>>>(y4c, W6, b6, c6c);
    dim3 g6(256 / 128, 512 / 64, 16);
    k_gemm<0, 0, 16><<<g6, 256, 0, stream>>>(y4c, Wr6, nullptr, p6, 512, 256, 16384);
    k_reduce6<<<512, 256, 0, stream>>>(p6, br6, s6, 512);
    k_topk<256, 64, 1><<<512, 256, 0, stream>>>(s6, c6c, y6 + (long)base * 4096);
  }

  dim3 g9(2048 / 128, 1024 / 64, 1);
  k_gemm<1, 0, 1><<<g9, 256, 0, stream>>>(y6, W9, b9, l9, 1024, 2048, 4096);
  k_gemm<0, 1, 1><<<g9, 256, 0, stream>>>(y6, Wr9, br9, s9, 1024, 2048, 4096);
  k_topk<2048, 512, 0><<<1024, 256, 0, stream>>>(s9, l9, y9);

  k_gemm<1, 0, 1><<<g9, 256, 0, stream>>>(y9, W11, b11, l11, 1024, 2048, 512);
  k_gemm<0, 1, 1><<<g9, 256, 0, stream>>>(y9, Wr11, br11, s11, 1024, 2048, 512);
  k_topk<2048, 512, 0><<<1024, 256, 0, stream>>>(s11, l11, y11);

  k_final<<<1024, 256, 0, stream>>>(y11, W13, b13, Wr13, br13, out);
}